// Round 1
// baseline (148.648 us; speedup 1.0000x reference)
//
#include <hip/hip_runtime.h>
#include <math.h>

#define NB 32
#define CC 512
#define HW 1024
#define NJ 10
#define DG 8

__device__ __forceinline__ float wave_reduce(float s) {
#pragma unroll
  for (int off = 32; off; off >>= 1) s += __shfl_down(s, off, 64);
  return s;
}

// K1: gap[n,c] = mean over HW. One block per (n,c), 256 threads x float4.
__global__ void k_gap(const float* __restrict__ x, float* __restrict__ gap) {
  int b = blockIdx.x;  // n*CC + c
  const float4* xp = (const float4*)(x + (size_t)b * HW);
  float4 v = xp[threadIdx.x];
  float s = v.x + v.y + v.z + v.w;
  s = wave_reduce(s);
  __shared__ float red[4];
  int lane = threadIdx.x & 63, wv = threadIdx.x >> 6;
  if (lane == 0) red[wv] = s;
  __syncthreads();
  if (threadIdx.x == 0)
    gap[b] = (red[0] + red[1] + red[2] + red[3]) * (1.0f / 1024.0f);
}

// K2: q = sigmoid(conv5(gap)+b); P_j = sum_c q^j; invZ = 1/sum_j P_j^2/j!
__global__ void k_qz(const float* __restrict__ gap, const float* __restrict__ wq,
                     const float* __restrict__ bq, float* __restrict__ q,
                     float* __restrict__ invZ) {
  int n = blockIdx.x, c = threadIdx.x;  // 512 threads
  const float* g = gap + n * CC;
  float z = bq[0];
#pragma unroll
  for (int j = 0; j < 5; ++j) {
    int idx = c + j - 2;
    float gv = (idx >= 0 && idx < CC) ? g[idx] : 0.0f;
    z = fmaf(gv, wq[j], z);
  }
  float qv = 1.0f / (1.0f + expf(-z));
  q[n * CC + c] = qv;
  float acc[NJ];
  {
    float w = 1.0f;
#pragma unroll
    for (int j = 0; j < NJ; ++j) { acc[j] = w; w *= qv; }
  }
#pragma unroll
  for (int j = 0; j < NJ; ++j) acc[j] = wave_reduce(acc[j]);
  __shared__ float red[NJ][8];
  int lane = c & 63, wv = c >> 6;
  if (lane == 0) {
#pragma unroll
    for (int j = 0; j < NJ; ++j) red[j][wv] = acc[j];
  }
  __syncthreads();
  if (c == 0) {
    const float cj[NJ] = {1.f, 1.f, 0.5f, 1.f / 6.f, 1.f / 24.f, 1.f / 120.f,
                          1.f / 720.f, 1.f / 5040.f, 1.f / 40320.f, 1.f / 362880.f};
    float Zv = 0.0f;
#pragma unroll
    for (int j = 0; j < NJ; ++j) {
      float P = 0.0f;
#pragma unroll
      for (int w8 = 0; w8 < 8; ++w8) P += red[j][w8];
      Zv = fmaf(cj[j] * P, P, Zv);
    }
    invZ[n] = 1.0f / Zv;
  }
}

// K4: partial moments sp[n,chunk,j,p] = sum_{c in chunk} q_c^j * x[n,c,p]
// block = (n, chunk); 256 threads each own 4 consecutive p (float4), i.e. all 1024 p.
__global__ void k_sj(const float* __restrict__ x, const float* __restrict__ q,
                     float* __restrict__ sp, int nchunk, int cs) {
  int b = blockIdx.x;
  int n = b / nchunk, ch = b - n * nchunk;
  int c0 = ch * cs;
  __shared__ float qs[CC];
  for (int i = threadIdx.x; i < cs; i += blockDim.x) qs[i] = q[n * CC + c0 + i];
  __syncthreads();
  float4 acc[NJ];
#pragma unroll
  for (int j = 0; j < NJ; ++j) acc[j] = make_float4(0.f, 0.f, 0.f, 0.f);
  const float4* xp = (const float4*)x + (size_t)(n * CC + c0) * (HW / 4) + threadIdx.x;
  for (int ci = 0; ci < cs; ++ci) {
    float4 xv = xp[(size_t)ci * (HW / 4)];
    float qc = qs[ci];
    float w = 1.0f;
#pragma unroll
    for (int j = 0; j < NJ; ++j) {
      acc[j].x = fmaf(w, xv.x, acc[j].x);
      acc[j].y = fmaf(w, xv.y, acc[j].y);
      acc[j].z = fmaf(w, xv.z, acc[j].z);
      acc[j].w = fmaf(w, xv.w, acc[j].w);
      w *= qc;
    }
  }
  float4* spp = (float4*)sp + (size_t)b * NJ * (HW / 4) + threadIdx.x;
#pragma unroll
  for (int j = 0; j < NJ; ++j) spp[j * (HW / 4)] = acc[j];
}

// K4b: s[n,j,p] = sum over chunks of sp
__global__ void k_red(const float* __restrict__ sp, float* __restrict__ s, int nchunk) {
  int b = blockIdx.x;  // n*NJ + j
  int n = b / NJ, j = b - n * NJ;
  float4 a = make_float4(0.f, 0.f, 0.f, 0.f);
  const float4* spp = (const float4*)sp;
  for (int ch = 0; ch < nchunk; ++ch) {
    float4 v = spp[((size_t)(n * nchunk + ch) * NJ + j) * (HW / 4) + threadIdx.x];
    a.x += v.x; a.y += v.y; a.z += v.z; a.w += v.w;
  }
  ((float4*)s)[(size_t)b * (HW / 4) + threadIdx.x] = a;
}

// K5: out[n,d,p] = x[n,d,p] * invZ * sum_j (q_d^j/j!) * s[n,j,p]
// block = (n, group of DG consecutive d); s fragment kept in registers across the group.
__global__ void k_out(const float* __restrict__ x, const float* __restrict__ q,
                      const float* __restrict__ s, const float* __restrict__ invZ,
                      float* __restrict__ out) {
  int b = blockIdx.x;
  int n = b / (CC / DG), dg = b - n * (CC / DG);
  int d0 = dg * DG;
  int t = threadIdx.x;
  const float4* s4 = (const float4*)s + (size_t)n * NJ * (HW / 4) + t;
  float4 sj[NJ];
#pragma unroll
  for (int j = 0; j < NJ; ++j) sj[j] = s4[j * (HW / 4)];
  float iz = invZ[n];
  const float cj[NJ] = {1.f, 1.f, 0.5f, 1.f / 6.f, 1.f / 24.f, 1.f / 120.f,
                        1.f / 720.f, 1.f / 5040.f, 1.f / 40320.f, 1.f / 362880.f};
#pragma unroll
  for (int di = 0; di < DG; ++di) {
    float qd = q[n * CC + d0 + di];
    float w = iz;  // fold invZ into the coefficients
    float4 att = make_float4(0.f, 0.f, 0.f, 0.f);
#pragma unroll
    for (int j = 0; j < NJ; ++j) {
      float a = cj[j] * w;
      att.x = fmaf(a, sj[j].x, att.x);
      att.y = fmaf(a, sj[j].y, att.y);
      att.z = fmaf(a, sj[j].z, att.z);
      att.w = fmaf(a, sj[j].w, att.w);
      w *= qd;
    }
    size_t idx = (size_t)(n * CC + d0 + di) * (HW / 4) + t;
    float4 xv = ((const float4*)x)[idx];
    float4 o;
    o.x = xv.x * att.x; o.y = xv.y * att.y;
    o.z = xv.z * att.z; o.w = xv.w * att.w;
    ((float4*)out)[idx] = o;
  }
}

extern "C" void kernel_launch(void* const* d_in, const int* in_sizes, int n_in,
                              void* d_out, int out_size, void* d_ws, size_t ws_size,
                              hipStream_t stream) {
  const float* x  = (const float*)d_in[0];
  const float* wq = (const float*)d_in[1];
  const float* bq = (const float*)d_in[2];
  float* out = (float*)d_out;
  char* ws = (char*)d_ws;

  float* gap  = (float*)(ws);                 // 64 KB
  float* q    = (float*)(ws + 65536);         // 64 KB
  float* invZ = (float*)(ws + 131072);        // 512 B reserved
  float* s    = (float*)(ws + 131584);        // NB*NJ*HW*4 = 1.25 MB
  size_t base = 131584 + (size_t)NB * NJ * HW * 4;
  float* sp   = (float*)(ws + base);

  int nchunk = 16;
  while (nchunk > 1 && base + (size_t)nchunk * NB * NJ * HW * 4 > ws_size) nchunk >>= 1;
  int cs = CC / nchunk;
  bool skip_red = false;
  if (base + (size_t)nchunk * NB * NJ * HW * 4 > ws_size) {
    // nchunk==1 and even single-chunk partials don't fit separately: write
    // partials straight into s (layout is identical for nchunk==1).
    sp = s; skip_red = true;
  }
  if (nchunk == 1) { sp = s; skip_red = true; }

  k_gap<<<NB * CC, 256, 0, stream>>>(x, gap);
  k_qz<<<NB, CC, 0, stream>>>(gap, wq, bq, q, invZ);
  k_sj<<<NB * nchunk, 256, 0, stream>>>(x, q, sp, nchunk, cs);
  if (!skip_red) k_red<<<NB * NJ, 256, 0, stream>>>(sp, s, nchunk);
  k_out<<<NB * (CC / DG), 256, 0, stream>>>(x, q, s, invZ, out);
}

// Round 2
// 131.313 us; speedup vs baseline: 1.1320x; 1.1320x over previous
//
#include <hip/hip_runtime.h>
#include <math.h>

#define NB 32
#define CC 512
#define HW 1024
#define NJ 10

__device__ __forceinline__ float wave_reduce(float s) {
#pragma unroll
  for (int off = 32; off; off >>= 1) s += __shfl_down(s, off, 64);
  return s;
}

// K1: gap[n,c] = mean over HW. 1024 blocks x 256 threads; each wave reduces
// 4 rows (4 outstanding float4 loads per lane per row for MLP).
__global__ __launch_bounds__(256) void k_gap(const float* __restrict__ x,
                                             float* __restrict__ gap) {
  int wv = threadIdx.x >> 6, lane = threadIdx.x & 63;
  int r0 = blockIdx.x * 16;
#pragma unroll
  for (int it = 0; it < 4; ++it) {
    int row = r0 + wv * 4 + it;
    const float4* xp = (const float4*)x + (size_t)row * 256;
    float s = 0.f;
#pragma unroll
    for (int k = 0; k < 4; ++k) {
      float4 v = xp[lane + 64 * k];
      s += v.x + v.y + v.z + v.w;
    }
    s = wave_reduce(s);
    if (lane == 0) gap[row] = s * (1.0f / 1024.0f);
  }
}

// K2: fully fused q/softmax-moments/output.
// Block = (n, pblk): all 512 channels x 64 spatial positions.
// Thread (cg,pg): holds x[cg*16..+15][pg*4..+3] in registers (16 float4).
//   phase Q: q=sigmoid(conv5(gap)), P_j partial sums -> invZ (redundant/block)
//   phase B: acc_j = sum_i q^j * xv[i]; reduce over cg (shfl-xor + LDS tree)
//            -> s_lds[pg][j] = invZ*(1/j!)*s_j  (final for this p-slice)
//   phase C: out = xv[i] * sum_j s_lds[pg][j] * q_d^j   (x never re-read)
__global__ __launch_bounds__(512) void k_fused(const float* __restrict__ x,
                                               const float* __restrict__ gap,
                                               const float* __restrict__ wq,
                                               const float* __restrict__ bq,
                                               float* __restrict__ out) {
  int n = blockIdx.x >> 4, pblk = blockIdx.x & 15;
  int t = threadIdx.x;
  int cg = t >> 4, pg = t & 15;
  int wv = t >> 6, lane = t & 63;

  __shared__ float qs[CC];
  __shared__ float wred[8][NJ];
  __shared__ float4 sred[8][16][NJ + 1];  // +1 float4 pad: lane stride 44f, no 4-way conflict
  __shared__ float4 sfin[16][NJ + 1];
  __shared__ float invZ_sh;

  const float cj[NJ] = {1.f, 1.f, 0.5f, 1.f / 6.f, 1.f / 24.f, 1.f / 120.f,
                        1.f / 720.f, 1.f / 5040.f, 1.f / 40320.f, 1.f / 362880.f};

  // ---- load x tile into registers (read x exactly once) ----
  float4 xv[16];
  const float4* x4 = (const float4*)x;
  size_t base = (size_t)(n * CC + cg * 16) * 256 + (size_t)pblk * 16 + pg;
#pragma unroll
  for (int i = 0; i < 16; ++i) xv[i] = x4[base + (size_t)i * 256];

  // ---- phase Q: q = sigmoid(conv5(gap)+b); wave partials of P_j ----
  {
    int c = t;  // 512 threads == 512 channels
    const float* g = gap + n * CC;
    float z = bq[0];
#pragma unroll
    for (int k = 0; k < 5; ++k) {
      int idx = c + k - 2;
      float gv = (idx >= 0 && idx < CC) ? g[idx] : 0.f;
      z = fmaf(gv, wq[k], z);
    }
    float qv = 1.f / (1.f + expf(-z));
    qs[c] = qv;
    float pj[NJ];
    float pw = 1.f;
#pragma unroll
    for (int j = 0; j < NJ; ++j) { pj[j] = pw; pw *= qv; }
#pragma unroll
    for (int j = 0; j < NJ; ++j) pj[j] = wave_reduce(pj[j]);
    if (lane == 0) {
#pragma unroll
      for (int j = 0; j < NJ; ++j) wred[wv][j] = pj[j];
    }
  }
  __syncthreads();
  if (t == 0) {
    float Z = 0.f;
#pragma unroll
    for (int j = 0; j < NJ; ++j) {
      float P = 0.f;
#pragma unroll
      for (int w8 = 0; w8 < 8; ++w8) P += wred[w8][j];
      Z = fmaf(cj[j] * P, P, Z);
    }
    invZ_sh = 1.f / Z;  // read after the NEXT __syncthreads
  }

  // ---- phase B: per-thread moment accumulation over 16 channels ----
  float4 acc[NJ];
#pragma unroll
  for (int j = 0; j < NJ; ++j) acc[j] = make_float4(0.f, 0.f, 0.f, 0.f);
#pragma unroll
  for (int i = 0; i < 16; ++i) {
    float qc = qs[cg * 16 + i];
    float4 v = xv[i];
    float w = 1.f;
#pragma unroll
    for (int j = 0; j < NJ; ++j) {
      acc[j].x = fmaf(w, v.x, acc[j].x);
      acc[j].y = fmaf(w, v.y, acc[j].y);
      acc[j].z = fmaf(w, v.z, acc[j].z);
      acc[j].w = fmaf(w, v.w, acc[j].w);
      w *= qc;
    }
  }
  // reduce over the 4 cg within this wave (lane bits 4,5)
#pragma unroll
  for (int j = 0; j < NJ; ++j) {
    acc[j].x += __shfl_xor(acc[j].x, 16, 64);
    acc[j].y += __shfl_xor(acc[j].y, 16, 64);
    acc[j].z += __shfl_xor(acc[j].z, 16, 64);
    acc[j].w += __shfl_xor(acc[j].w, 16, 64);
    acc[j].x += __shfl_xor(acc[j].x, 32, 64);
    acc[j].y += __shfl_xor(acc[j].y, 32, 64);
    acc[j].z += __shfl_xor(acc[j].z, 32, 64);
    acc[j].w += __shfl_xor(acc[j].w, 32, 64);
  }
  if (lane < 16) {
#pragma unroll
    for (int j = 0; j < NJ; ++j) sred[wv][lane][j] = acc[j];
  }
  __syncthreads();
  // cross-wave tree: 160 bins (16 pg x 10 j), fold in invZ * 1/j!
  if (t < 160) {
    int pp = t / NJ, j = t - pp * NJ;
    float4 a = make_float4(0.f, 0.f, 0.f, 0.f);
#pragma unroll
    for (int w8 = 0; w8 < 8; ++w8) {
      float4 v = sred[w8][pp][j];
      a.x += v.x; a.y += v.y; a.z += v.z; a.w += v.w;
    }
    float sc = cj[j] * invZ_sh;
    a.x *= sc; a.y *= sc; a.z *= sc; a.w *= sc;
    sfin[pp][j] = a;
  }
  __syncthreads();

  // ---- phase C: out = x * att, x still in registers ----
  float4 sj[NJ];
#pragma unroll
  for (int j = 0; j < NJ; ++j) sj[j] = sfin[pg][j];
  float4* o4 = (float4*)out;
#pragma unroll
  for (int i = 0; i < 16; ++i) {
    float qd = qs[cg * 16 + i];
    float w = 1.f;
    float4 att = make_float4(0.f, 0.f, 0.f, 0.f);
#pragma unroll
    for (int j = 0; j < NJ; ++j) {
      att.x = fmaf(w, sj[j].x, att.x);
      att.y = fmaf(w, sj[j].y, att.y);
      att.z = fmaf(w, sj[j].z, att.z);
      att.w = fmaf(w, sj[j].w, att.w);
      w *= qd;
    }
    float4 xvv = xv[i];
    float4 o;
    o.x = xvv.x * att.x; o.y = xvv.y * att.y;
    o.z = xvv.z * att.z; o.w = xvv.w * att.w;
    o4[base + (size_t)i * 256] = o;
  }
}

extern "C" void kernel_launch(void* const* d_in, const int* in_sizes, int n_in,
                              void* d_out, int out_size, void* d_ws, size_t ws_size,
                              hipStream_t stream) {
  const float* x  = (const float*)d_in[0];
  const float* wq = (const float*)d_in[1];
  const float* bq = (const float*)d_in[2];
  float* out = (float*)d_out;
  float* gap = (float*)d_ws;  // NB*CC floats = 64 KB

  k_gap<<<NB * CC / 16, 256, 0, stream>>>(x, gap);
  k_fused<<<NB * 16, 512, 0, stream>>>(x, gap, wq, bq, out);
}